// Round 1
// baseline (1419.636 us; speedup 1.0000x reference)
//
#include <hip/hip_runtime.h>

#define N_NODES 50000
#define IN_DIM 512
#define OUT_DIM 128
#define N_EDGES 1600000

// ---------------------------------------------------------------------------
// GEMM: xw[N_NODES, 128] = x[N_NODES, 512] @ W[512, 128]   (f32, LDS-tiled)
// block = 256 threads, tile BM=64 rows x BN=128 cols, BK=32.
// Each thread computes an 8x4 micro-tile (rows tr*8..tr*8+7, cols tc*4..tc*4+3).
// ---------------------------------------------------------------------------
constexpr int BM = 64;
constexpr int BK = 32;

__global__ __launch_bounds__(256) void gemm_xw(const float* __restrict__ x,
                                               const float* __restrict__ w,
                                               float* __restrict__ xw) {
    __shared__ float xs[BM][BK];        // 8 KB
    __shared__ float ws[BK][OUT_DIM];   // 16 KB
    const int tid = threadIdx.x;
    const int block_row = blockIdx.x * BM;
    const int tc = tid & 31;   // column group: cols tc*4 .. tc*4+3
    const int tr = tid >> 5;   // row group: rows tr*8 .. tr*8+7

    float acc[8][4];
#pragma unroll
    for (int i = 0; i < 8; ++i)
#pragma unroll
        for (int j = 0; j < 4; ++j) acc[i][j] = 0.f;

    for (int k0 = 0; k0 < IN_DIM; k0 += BK) {
        // Stage x tile: 64x32 = 2048 f32 = 512 float4; 2 per thread, coalesced.
#pragma unroll
        for (int it = 0; it < 2; ++it) {
            int f = tid + it * 256;       // float4 index in flat tile
            int r = f >> 3;               // (f*4)/32
            int kk = (f & 7) * 4;
            int grow = block_row + r;
            float4 v = make_float4(0.f, 0.f, 0.f, 0.f);
            if (grow < N_NODES)
                v = *reinterpret_cast<const float4*>(&x[(size_t)grow * IN_DIM + k0 + kk]);
            *reinterpret_cast<float4*>(&xs[r][kk]) = v;
        }
        // Stage W tile: 32x128 = 4096 f32 = 1024 float4; 4 per thread, coalesced.
#pragma unroll
        for (int it = 0; it < 4; ++it) {
            int g = tid + it * 256;
            int kk = g >> 5;              // (g*4)/128
            int cc = (g & 31) * 4;
            float4 v = *reinterpret_cast<const float4*>(&w[(size_t)(k0 + kk) * OUT_DIM + cc]);
            *reinterpret_cast<float4*>(&ws[kk][cc]) = v;
        }
        __syncthreads();

#pragma unroll
        for (int kk = 0; kk < BK; ++kk) {
            float4 wv = *reinterpret_cast<const float4*>(&ws[kk][tc * 4]);
#pragma unroll
            for (int i = 0; i < 8; ++i) {
                float xv = xs[tr * 8 + i][kk];
                acc[i][0] = fmaf(xv, wv.x, acc[i][0]);
                acc[i][1] = fmaf(xv, wv.y, acc[i][1]);
                acc[i][2] = fmaf(xv, wv.z, acc[i][2]);
                acc[i][3] = fmaf(xv, wv.w, acc[i][3]);
            }
        }
        __syncthreads();
    }

#pragma unroll
    for (int i = 0; i < 8; ++i) {
        int grow = block_row + tr * 8 + i;
        if (grow < N_NODES) {
            float4 v = make_float4(acc[i][0], acc[i][1], acc[i][2], acc[i][3]);
            *reinterpret_cast<float4*>(&xw[(size_t)grow * OUT_DIM + tc * 4]) = v;
        }
    }
}

// ---------------------------------------------------------------------------
// COO SpMM scatter: out[row[e]][d] += val[e] * xw[col[e]][d]
// One 64-thread group per edge; each thread handles 2 dims (float2 gather,
// 2 scalar f32 atomics). Gathers hit L2/L3 (xw is 25.6 MB).
// ---------------------------------------------------------------------------
__global__ __launch_bounds__(256) void scatter_edges(const float* __restrict__ xw,
                                                     const int* __restrict__ erow,
                                                     const int* __restrict__ ecol,
                                                     const float* __restrict__ eval_,
                                                     float* __restrict__ out) {
    long long gid = (long long)blockIdx.x * 256 + threadIdx.x;
    int e = (int)(gid >> 6);
    if (e >= N_EDGES) return;
    int d = (int)(gid & 63) * 2;
    int r = erow[e];
    int c = ecol[e];
    float v = eval_[e];
    float2 m = *reinterpret_cast<const float2*>(&xw[(size_t)c * OUT_DIM + d]);
    atomicAdd(&out[(size_t)r * OUT_DIM + d],     v * m.x);
    atomicAdd(&out[(size_t)r * OUT_DIM + d + 1], v * m.y);
}

// ---------------------------------------------------------------------------
// ReLU epilogue (in place on d_out)
// ---------------------------------------------------------------------------
__global__ __launch_bounds__(256) void relu_inplace(float* __restrict__ out, int n4) {
    int i = blockIdx.x * 256 + threadIdx.x;
    if (i < n4) {
        float4 v = reinterpret_cast<float4*>(out)[i];
        v.x = fmaxf(v.x, 0.f);
        v.y = fmaxf(v.y, 0.f);
        v.z = fmaxf(v.z, 0.f);
        v.w = fmaxf(v.w, 0.f);
        reinterpret_cast<float4*>(out)[i] = v;
    }
}

extern "C" void kernel_launch(void* const* d_in, const int* in_sizes, int n_in,
                              void* d_out, int out_size, void* d_ws, size_t ws_size,
                              hipStream_t stream) {
    const float* x     = (const float*)d_in[0];
    const float* w     = (const float*)d_in[1];
    const int*   erow  = (const int*)d_in[2];
    const int*   ecol  = (const int*)d_in[3];
    const float* eval_ = (const float*)d_in[4];
    float* out = (float*)d_out;
    float* xw  = (float*)d_ws;   // 50000*128*4 = 25.6 MB scratch

    // Zero the accumulator (d_out is poisoned to 0xAA by the harness).
    hipMemsetAsync(d_out, 0, (size_t)N_NODES * OUT_DIM * sizeof(float), stream);

    // 1) Dense transform
    gemm_xw<<<(N_NODES + BM - 1) / BM, 256, 0, stream>>>(x, w, xw);

    // 2) Sparse aggregation (atomics)
    long long total = (long long)N_EDGES * 64;
    int blocks = (int)((total + 255) / 256);
    scatter_edges<<<blocks, 256, 0, stream>>>(xw, erow, ecol, eval_, out);

    // 3) Activation
    int n4 = N_NODES * OUT_DIM / 4;
    relu_inplace<<<(n4 + 255) / 256, 256, 0, stream>>>(out, n4);
}

// Round 2
// 448.895 us; speedup vs baseline: 3.1625x; 3.1625x over previous
//
#include <hip/hip_runtime.h>

#define N_NODES 50000
#define IN_DIM 512
#define OUT_DIM 128
#define N_EDGES 1600000

// ---------------------------------------------------------------------------
// Workspace layout (bytes, all 64B-aligned):
//   [0)            xw        : 50000*128 f32   = 25,600,000
//   [25,600,000)   offs      : (N_NODES+1) int = 200,004  (padded)
//   [25,800,064)   cursor    : N_NODES int     = 200,000  (padded)
//   [26,000,128)   csr_pack  : N_EDGES int2    = 12,800,000
// total ~38.8 MB
// ---------------------------------------------------------------------------
constexpr size_t OFF_XW   = 0;
constexpr size_t OFF_OFFS = 25600000;
constexpr size_t OFF_CUR  = 25800064;
constexpr size_t OFF_CSR  = 26000128;

// ---------------------------------------------------------------------------
// GEMM: xw[N,128] = x[N,512] @ W[512,128]  (f32, LDS-tiled) — unchanged
// ---------------------------------------------------------------------------
constexpr int BM = 64;
constexpr int BK = 32;

__global__ __launch_bounds__(256) void gemm_xw(const float* __restrict__ x,
                                               const float* __restrict__ w,
                                               float* __restrict__ xw) {
    __shared__ float xs[BM][BK];
    __shared__ float ws[BK][OUT_DIM];
    const int tid = threadIdx.x;
    const int block_row = blockIdx.x * BM;
    const int tc = tid & 31;
    const int tr = tid >> 5;

    float acc[8][4];
#pragma unroll
    for (int i = 0; i < 8; ++i)
#pragma unroll
        for (int j = 0; j < 4; ++j) acc[i][j] = 0.f;

    for (int k0 = 0; k0 < IN_DIM; k0 += BK) {
#pragma unroll
        for (int it = 0; it < 2; ++it) {
            int f = tid + it * 256;
            int r = f >> 3;
            int kk = (f & 7) * 4;
            int grow = block_row + r;
            float4 v = make_float4(0.f, 0.f, 0.f, 0.f);
            if (grow < N_NODES)
                v = *reinterpret_cast<const float4*>(&x[(size_t)grow * IN_DIM + k0 + kk]);
            *reinterpret_cast<float4*>(&xs[r][kk]) = v;
        }
#pragma unroll
        for (int it = 0; it < 4; ++it) {
            int g = tid + it * 256;
            int kk = g >> 5;
            int cc = (g & 31) * 4;
            float4 v = *reinterpret_cast<const float4*>(&w[(size_t)(k0 + kk) * OUT_DIM + cc]);
            *reinterpret_cast<float4*>(&ws[kk][cc]) = v;
        }
        __syncthreads();

#pragma unroll
        for (int kk = 0; kk < BK; ++kk) {
            float4 wv = *reinterpret_cast<const float4*>(&ws[kk][tc * 4]);
#pragma unroll
            for (int i = 0; i < 8; ++i) {
                float xv = xs[tr * 8 + i][kk];
                acc[i][0] = fmaf(xv, wv.x, acc[i][0]);
                acc[i][1] = fmaf(xv, wv.y, acc[i][1]);
                acc[i][2] = fmaf(xv, wv.z, acc[i][2]);
                acc[i][3] = fmaf(xv, wv.w, acc[i][3]);
            }
        }
        __syncthreads();
    }

#pragma unroll
    for (int i = 0; i < 8; ++i) {
        int grow = block_row + tr * 8 + i;
        if (grow < N_NODES) {
            float4 v = make_float4(acc[i][0], acc[i][1], acc[i][2], acc[i][3]);
            *reinterpret_cast<float4*>(&xw[(size_t)grow * OUT_DIM + tc * 4]) = v;
        }
    }
}

// ---------------------------------------------------------------------------
// CSR build: counting sort by row.
// ---------------------------------------------------------------------------
__global__ __launch_bounds__(256) void hist_rows(const int* __restrict__ erow,
                                                 int* __restrict__ cnt /* = offs+1 */) {
    int e = blockIdx.x * 256 + threadIdx.x;
    if (e < N_EDGES) atomicAdd(&cnt[erow[e]], 1);
}

// Inclusive scan in place over offs[1..N_NODES]; offs[0] stays 0.
__global__ __launch_bounds__(1024) void scan_offsets(int* __restrict__ offs) {
    __shared__ int partials[1024];
    const int tid = threadIdx.x;
    const int CHUNK = (N_NODES + 1023) / 1024;  // 49
    int begin = 1 + tid * CHUNK;
    int end = begin + CHUNK;
    if (end > N_NODES + 1) end = N_NODES + 1;

    int sum = 0;
    for (int i = begin; i < end; ++i) sum += offs[i];
    partials[tid] = sum;
    __syncthreads();
    // Hillis-Steele inclusive scan of 1024 partials
    for (int d = 1; d < 1024; d <<= 1) {
        int v = (tid >= d) ? partials[tid - d] : 0;
        __syncthreads();
        partials[tid] += v;
        __syncthreads();
    }
    int run = (tid == 0) ? 0 : partials[tid - 1];
    for (int i = begin; i < end; ++i) {
        run += offs[i];
        offs[i] = run;
    }
}

__global__ __launch_bounds__(256) void build_csr(const int* __restrict__ erow,
                                                 const int* __restrict__ ecol,
                                                 const float* __restrict__ eval_,
                                                 const int* __restrict__ offs,
                                                 int* __restrict__ cursor,
                                                 int2* __restrict__ csr) {
    int e = blockIdx.x * 256 + threadIdx.x;
    if (e < N_EDGES) {
        int r = erow[e];
        int pos = offs[r] + atomicAdd(&cursor[r], 1);
        csr[pos] = make_int2(ecol[e], __float_as_int(eval_[e]));
    }
}

// ---------------------------------------------------------------------------
// Aggregate: one wave per output row; lane d owns dims {2d, 2d+1}.
// Per edge: 8B broadcast (col,val) + coalesced 512B gather of xw[col][:].
// ReLU fused; each output element written exactly once.
// ---------------------------------------------------------------------------
__global__ __launch_bounds__(256) void aggregate_csr(const int2* __restrict__ csr,
                                                     const int* __restrict__ offs,
                                                     const float* __restrict__ xw,
                                                     float* __restrict__ out) {
    int wave = blockIdx.x * 4 + (threadIdx.x >> 6);
    if (wave >= N_NODES) return;
    int lane = threadIdx.x & 63;
    int start = offs[wave];
    int end = offs[wave + 1];

    float a0 = 0.f, a1 = 0.f, b0 = 0.f, b1 = 0.f;
    int i = start;
    for (; i + 1 < end; i += 2) {
        int2 p0 = csr[i];
        int2 p1 = csr[i + 1];
        float2 m0 = *reinterpret_cast<const float2*>(&xw[(size_t)p0.x * OUT_DIM + lane * 2]);
        float2 m1 = *reinterpret_cast<const float2*>(&xw[(size_t)p1.x * OUT_DIM + lane * 2]);
        float v0 = __int_as_float(p0.y);
        float v1 = __int_as_float(p1.y);
        a0 = fmaf(v0, m0.x, a0);
        a1 = fmaf(v0, m0.y, a1);
        b0 = fmaf(v1, m1.x, b0);
        b1 = fmaf(v1, m1.y, b1);
    }
    if (i < end) {
        int2 p = csr[i];
        float v = __int_as_float(p.y);
        float2 m = *reinterpret_cast<const float2*>(&xw[(size_t)p.x * OUT_DIM + lane * 2]);
        a0 = fmaf(v, m.x, a0);
        a1 = fmaf(v, m.y, a1);
    }
    float2 r = make_float2(fmaxf(a0 + b0, 0.f), fmaxf(a1 + b1, 0.f));
    *reinterpret_cast<float2*>(&out[(size_t)wave * OUT_DIM + lane * 2]) = r;
}

extern "C" void kernel_launch(void* const* d_in, const int* in_sizes, int n_in,
                              void* d_out, int out_size, void* d_ws, size_t ws_size,
                              hipStream_t stream) {
    const float* x     = (const float*)d_in[0];
    const float* w     = (const float*)d_in[1];
    const int*   erow  = (const int*)d_in[2];
    const int*   ecol  = (const int*)d_in[3];
    const float* eval_ = (const float*)d_in[4];
    float* out = (float*)d_out;

    char* ws = (char*)d_ws;
    float* xw    = (float*)(ws + OFF_XW);
    int*   offs  = (int*)(ws + OFF_OFFS);
    int*   cursor= (int*)(ws + OFF_CUR);
    int2*  csr   = (int2*)(ws + OFF_CSR);

    // Zero offs + cursor region (contiguous).
    hipMemsetAsync(ws + OFF_OFFS, 0, OFF_CSR - OFF_OFFS, stream);

    // 1) Dense transform
    gemm_xw<<<(N_NODES + BM - 1) / BM, 256, 0, stream>>>(x, w, xw);

    // 2) CSR build (counting sort by row)
    int eblocks = (N_EDGES + 255) / 256;
    hist_rows<<<eblocks, 256, 0, stream>>>(erow, offs + 1);
    scan_offsets<<<1, 1024, 0, stream>>>(offs);
    build_csr<<<eblocks, 256, 0, stream>>>(erow, ecol, eval_, offs, cursor, csr);

    // 3) Gather-side aggregation + fused ReLU (one wave per row)
    int ablocks = (N_NODES + 3) / 4;
    aggregate_csr<<<ablocks, 256, 0, stream>>>(csr, offs, xw, out);
}

// Round 3
// 353.655 us; speedup vs baseline: 4.0142x; 1.2693x over previous
//
#include <hip/hip_runtime.h>

#define N_NODES 50000
#define IN_DIM 512
#define OUT_DIM 128
#define N_EDGES 1600000

typedef __attribute__((ext_vector_type(8))) short short8;
typedef __attribute__((ext_vector_type(4))) float floatx4;

__device__ __forceinline__ ushort f2bf(float f) {
    uint u = __float_as_uint(f);
    u += 0x7FFFu + ((u >> 16) & 1u);   // round-to-nearest-even
    return (ushort)(u >> 16);
}

// ---------------------------------------------------------------------------
// Workspace layout (bytes):
//   [0)          xwb    : 50000*128 bf16 = 12,800,000
//   [12,800,000) wt     : 128*512 bf16   = 131,072   (Wt[c][k] = W[k][c])
//   [13,000,000) offs   : (N_NODES+1) int
//   [13,200,064) cursor : N_NODES int
//   [13,400,128) csr    : N_EDGES int2   = 12,800,000
// ---------------------------------------------------------------------------
constexpr size_t OFF_XWB  = 0;
constexpr size_t OFF_WT   = 12800000;
constexpr size_t OFF_OFFS = 13000000;
constexpr size_t OFF_CUR  = 13200064;
constexpr size_t OFF_CSR  = 13400128;

// ---------------------------------------------------------------------------
// W transpose+convert: Wt[c][k] = bf16(W[k][c])   (tiny: 64K elements)
// ---------------------------------------------------------------------------
__global__ __launch_bounds__(256) void conv_wt(const float* __restrict__ w,
                                               ushort* __restrict__ wt) {
    int t = blockIdx.x * 256 + threadIdx.x;
    if (t < IN_DIM * OUT_DIM) {
        int k = t >> 7;          // 0..511
        int c = t & 127;         // 0..127
        wt[(size_t)c * IN_DIM + k] = f2bf(w[t]);
    }
}

// ---------------------------------------------------------------------------
// GEMM: xwb[N,128](bf16) = x[N,512](f32) @ W  via mfma_f32_16x16x32_bf16.
// Block: 256 thr (4 waves), tile 64 rows x 128 cols, BK=64.
// Wave w owns rows w*16..w*16+15; 8 col-tiles of 16.
// LDS XOR-swizzle: byte ^= ((row&7)<<4) within each 128B row (T2/G4).
// ---------------------------------------------------------------------------
__global__ __launch_bounds__(256) void gemm_xw_mfma(const float* __restrict__ x,
                                                    const ushort* __restrict__ wt,
                                                    ushort* __restrict__ xwb) {
    __shared__ char Alds[64 * 128];    // 8 KB : 64 rows x 64 bf16 (swizzled)
    __shared__ char Blds[128 * 128];   // 16 KB: 128 cols x 64 bf16 (swizzled)
    const int tid = threadIdx.x;
    const int w = tid >> 6;
    const int lane = tid & 63;
    const int block_row = blockIdx.x * 64;

    floatx4 acc[8];
#pragma unroll
    for (int i = 0; i < 8; ++i) acc[i] = (floatx4){0.f, 0.f, 0.f, 0.f};

    for (int k0 = 0; k0 < IN_DIM; k0 += 64) {
        // Stage A: 64x64 f32 -> bf16, swizzled. 4 float4 per thread, coalesced.
#pragma unroll
        for (int it = 0; it < 4; ++it) {
            int f4 = tid + it * 256;       // 0..1023
            int r = f4 >> 4;               // row 0..63
            int f4c = f4 & 15;             // float4 index within row
            int grow = block_row + r;
            float4 v = make_float4(0.f, 0.f, 0.f, 0.f);
            if (grow < N_NODES)
                v = *reinterpret_cast<const float4*>(&x[(size_t)grow * IN_DIM + k0 + f4c * 4]);
            ushort4 b = make_ushort4(f2bf(v.x), f2bf(v.y), f2bf(v.z), f2bf(v.w));
            int off = r * 128 + ((f4c * 8) ^ ((r & 7) << 4));
            *reinterpret_cast<ushort4*>(Alds + off) = b;   // 8B store
        }
        // Stage B: Wt[c][k0..k0+64) -> 128 rows x 128B, swizzled. 16B per thread x4.
#pragma unroll
        for (int it = 0; it < 4; ++it) {
            int j = tid * 16 + it * 4096;  // linear byte in tile
            int c = j >> 7;                // col 0..127
            int inner = j & 127;
            ulonglong2 v = *reinterpret_cast<const ulonglong2*>(
                reinterpret_cast<const char*>(wt) + (size_t)c * 1024 + k0 * 2 + inner);
            int off = c * 128 + (inner ^ ((c & 7) << 4));
            *reinterpret_cast<ulonglong2*>(Blds + off) = v; // 16B store
        }
        __syncthreads();

#pragma unroll
        for (int kb = 0; kb < 2; ++kb) {              // two K=32 halves
            int ar = w * 16 + (lane & 15);
            int koffb = kb * 64 + (lane >> 4) * 16;   // byte offset along K
            short8 afrag = *reinterpret_cast<const short8*>(
                Alds + ar * 128 + (koffb ^ ((ar & 7) << 4)));
#pragma unroll
            for (int ct = 0; ct < 8; ++ct) {
                int bc = ct * 16 + (lane & 15);
                short8 bfrag = *reinterpret_cast<const short8*>(
                    Blds + bc * 128 + (koffb ^ ((bc & 7) << 4)));
                acc[ct] = __builtin_amdgcn_mfma_f32_16x16x32_bf16(afrag, bfrag, acc[ct], 0, 0, 0);
            }
        }
        __syncthreads();
    }

    // Epilogue: C/D layout col=lane&15, row=(lane>>4)*4+reg (m89-verified).
    const int orow0 = block_row + w * 16 + (lane >> 4) * 4;
    const int ocol = lane & 15;
#pragma unroll
    for (int ct = 0; ct < 8; ++ct) {
#pragma unroll
        for (int i = 0; i < 4; ++i) {
            int grow = orow0 + i;
            if (grow < N_NODES)
                xwb[(size_t)grow * OUT_DIM + ct * 16 + ocol] = f2bf(acc[ct][i]);
        }
    }
}

// ---------------------------------------------------------------------------
// CSR build: counting sort by row.
// ---------------------------------------------------------------------------
__global__ __launch_bounds__(256) void hist_rows(const int* __restrict__ erow,
                                                 int* __restrict__ cnt) {
    int e = blockIdx.x * 256 + threadIdx.x;
    if (e < N_EDGES) atomicAdd(&cnt[erow[e]], 1);
}

__global__ __launch_bounds__(1024) void scan_offsets(int* __restrict__ offs) {
    __shared__ int partials[1024];
    const int tid = threadIdx.x;
    const int CHUNK = (N_NODES + 1023) / 1024;  // 49
    int begin = 1 + tid * CHUNK;
    int end = begin + CHUNK;
    if (end > N_NODES + 1) end = N_NODES + 1;

    int sum = 0;
    for (int i = begin; i < end; ++i) sum += offs[i];
    partials[tid] = sum;
    __syncthreads();
    for (int d = 1; d < 1024; d <<= 1) {
        int v = (tid >= d) ? partials[tid - d] : 0;
        __syncthreads();
        partials[tid] += v;
        __syncthreads();
    }
    int run = (tid == 0) ? 0 : partials[tid - 1];
    for (int i = begin; i < end; ++i) {
        run += offs[i];
        offs[i] = run;
    }
}

__global__ __launch_bounds__(256) void build_csr(const int* __restrict__ erow,
                                                 const int* __restrict__ ecol,
                                                 const float* __restrict__ eval_,
                                                 const int* __restrict__ offs,
                                                 int* __restrict__ cursor,
                                                 int2* __restrict__ csr) {
    int e = blockIdx.x * 256 + threadIdx.x;
    if (e < N_EDGES) {
        int r = erow[e];
        int pos = offs[r] + atomicAdd(&cursor[r], 1);
        csr[pos] = make_int2(ecol[e], __float_as_int(eval_[e]));
    }
}

// ---------------------------------------------------------------------------
// Aggregate: one wave per row; lane owns dims {2*lane, 2*lane+1} via one u32
// (2xbf16) gather -> 256B/edge/wave. ReLU fused; single write per element.
// ---------------------------------------------------------------------------
__global__ __launch_bounds__(256) void aggregate_csr(const int2* __restrict__ csr,
                                                     const int* __restrict__ offs,
                                                     const ushort* __restrict__ xwb,
                                                     float* __restrict__ out) {
    int row = blockIdx.x * 4 + (threadIdx.x >> 6);
    if (row >= N_NODES) return;
    int lane = threadIdx.x & 63;
    int start = offs[row];
    int end = offs[row + 1];
    const uint* base = reinterpret_cast<const uint*>(xwb);  // [c][lane] u32 = 2 bf16

    float a0 = 0.f, a1 = 0.f, b0 = 0.f, b1 = 0.f;
    int i = start;
    for (; i + 1 < end; i += 2) {
        int2 p0 = csr[i];
        int2 p1 = csr[i + 1];
        uint m0 = base[(size_t)p0.x * 64 + lane];
        uint m1 = base[(size_t)p1.x * 64 + lane];
        float v0 = __int_as_float(p0.y);
        float v1 = __int_as_float(p1.y);
        a0 = fmaf(v0, __uint_as_float(m0 << 16), a0);
        a1 = fmaf(v0, __uint_as_float(m0 & 0xFFFF0000u), a1);
        b0 = fmaf(v1, __uint_as_float(m1 << 16), b0);
        b1 = fmaf(v1, __uint_as_float(m1 & 0xFFFF0000u), b1);
    }
    if (i < end) {
        int2 p = csr[i];
        uint m = base[(size_t)p.x * 64 + lane];
        float v = __int_as_float(p.y);
        a0 = fmaf(v, __uint_as_float(m << 16), a0);
        a1 = fmaf(v, __uint_as_float(m & 0xFFFF0000u), a1);
    }
    float2 r = make_float2(fmaxf(a0 + b0, 0.f), fmaxf(a1 + b1, 0.f));
    *reinterpret_cast<float2*>(&out[(size_t)row * OUT_DIM + lane * 2]) = r;
}

extern "C" void kernel_launch(void* const* d_in, const int* in_sizes, int n_in,
                              void* d_out, int out_size, void* d_ws, size_t ws_size,
                              hipStream_t stream) {
    const float* x     = (const float*)d_in[0];
    const float* w     = (const float*)d_in[1];
    const int*   erow  = (const int*)d_in[2];
    const int*   ecol  = (const int*)d_in[3];
    const float* eval_ = (const float*)d_in[4];
    float* out = (float*)d_out;

    char* ws = (char*)d_ws;
    ushort* xwb   = (ushort*)(ws + OFF_XWB);
    ushort* wt    = (ushort*)(ws + OFF_WT);
    int*    offs  = (int*)(ws + OFF_OFFS);
    int*    cursor= (int*)(ws + OFF_CUR);
    int2*   csr   = (int2*)(ws + OFF_CSR);

    // Zero offs + cursor (contiguous range).
    hipMemsetAsync(ws + OFF_OFFS, 0, OFF_CSR - OFF_OFFS, stream);

    // W transpose+convert (tiny)
    conv_wt<<<(IN_DIM * OUT_DIM + 255) / 256, 256, 0, stream>>>(w, wt);

    // CSR histogram can go before GEMM (independent)
    int eblocks = (N_EDGES + 255) / 256;
    hist_rows<<<eblocks, 256, 0, stream>>>(erow, offs + 1);
    scan_offsets<<<1, 1024, 0, stream>>>(offs);

    // Dense transform (MFMA bf16)
    gemm_xw_mfma<<<(N_NODES + 63) / 64, 256, 0, stream>>>(x, wt, xwb);

    build_csr<<<eblocks, 256, 0, stream>>>(erow, ecol, eval_, offs, cursor, csr);

    // Gather-side aggregation + fused ReLU
    aggregate_csr<<<(N_NODES + 3) / 4, 256, 0, stream>>>(csr, offs, xwb, out);
}